// Round 3
// baseline (439.481 us; speedup 1.0000x reference)
//
#include <hip/hip_runtime.h>
#include <stdint.h>

// Problem constants
#define T_TOK 16384     // 32*512 tokens
#define NE 8            // experts
#define EPSV 1e-8f
#define MAXC128 136     // max 128-token chunks: 128 + 7 partials, rounded up
#define MAXC64  264     // max 64-token chunks: 256 + 7 partials, rounded up

// ws layout (byte offsets). Total ~59.1 MB.
#define WS_PERM   0                         // int[16384]
#define WS_CE128  65568
#define WS_CB128  66112
#define WS_CL128  66656
#define WS_CE64   67200
#define WS_CB64   68256
#define WS_CL64   69312
#define WS_XS     131072                    // bf16[16512][1024] (128 slack rows for OOB-safe tile loads)
#define WS_WT     (WS_XS + 16512*1024*2)    // bf16[8][512][1024]  (W1|R1 transposed, B^T layout)
#define WS_H1     (WS_WT + 8*512*1024*2)    // bf16[16384][512]

typedef __attribute__((ext_vector_type(8))) short bf16x8;
typedef __attribute__((ext_vector_type(4))) float f32x4;

__device__ __forceinline__ unsigned short f2bf(float f) {
    unsigned u = __float_as_uint(f);
    u += 0x7fffu + ((u >> 16) & 1u);   // RNE
    return (unsigned short)(u >> 16);
}
__device__ __forceinline__ float bf2f(unsigned short h) {
    return __uint_as_float(((unsigned)h) << 16);
}

// ---------------- kernel 1: histogram + scan + chunk tables + scatter ----------------
__global__ __launch_bounds__(256) void k_prep(const int* __restrict__ sem, int* __restrict__ ws_i) {
    __shared__ int cnt[NE];
    __shared__ int cur[NE];
    int tid = threadIdx.x;
    int lane = tid & 63;
    if (tid < NE) cnt[tid] = 0;
    __syncthreads();
    // histogram via per-wave ballots (8 LDS atomics per wave-iter)
    for (int i = tid; i < T_TOK; i += 256) {
        int s = sem[i];
#pragma unroll
        for (int e = 0; e < NE; e++) {
            unsigned long long m = __ballot(s == e);
            if (lane == e) atomicAdd(&cnt[e], (int)__popcll(m));
        }
    }
    __syncthreads();
    if (tid == 0) {
        int* ce128 = ws_i + (WS_CE128 >> 2);
        int* cb128 = ws_i + (WS_CB128 >> 2);
        int* cl128 = ws_i + (WS_CL128 >> 2);
        int* ce64  = ws_i + (WS_CE64 >> 2);
        int* cb64  = ws_i + (WS_CB64 >> 2);
        int* cl64  = ws_i + (WS_CL64 >> 2);
        int acc = 0, i128 = 0, i64 = 0;
        for (int e = 0; e < NE; e++) {
            int c = cnt[e];
            cur[e] = acc;
            for (int j = 0; j < c; j += 128) {
                ce128[i128] = e; cb128[i128] = acc + j;
                cl128[i128] = (c - j < 128) ? (c - j) : 128; i128++;
            }
            for (int j = 0; j < c; j += 64) {
                ce64[i64] = e; cb64[i64] = acc + j;
                cl64[i64] = (c - j < 64) ? (c - j) : 64; i64++;
            }
            acc += c;
        }
        for (; i128 < MAXC128; i128++) cl128[i128] = 0;
        for (; i64  < MAXC64;  i64++ ) cl64[i64]  = 0;
    }
    __syncthreads();
    // scatter: perm[sorted_pos] = token
    int* perm = ws_i + (WS_PERM >> 2);
    for (int i = tid; i < T_TOK; i += 256) {
        int s = sem[i];
#pragma unroll
        for (int e = 0; e < NE; e++) {
            unsigned long long m = __ballot(s == e);
            if (s == e) {
                int leader = (int)__builtin_ctzll(m);
                int rank = (int)__popcll(m & ((1ull << lane) - 1ull));
                int bpos = 0;
                if (lane == leader) bpos = atomicAdd(&cur[e], (int)__popcll(m));
                bpos = __shfl(bpos, leader, 64);
                perm[bpos + rank] = i;
            }
        }
    }
}

// ---------------- kernel 2: gather + fp32->bf16 convert of nodes ----------------
__global__ __launch_bounds__(256) void k_xgather(const float* __restrict__ x,
                                                 const int* __restrict__ perm,
                                                 unsigned short* __restrict__ xs) {
    int gid = blockIdx.x * 256 + threadIdx.x;    // 0 .. 2097151
    int st = gid >> 7;                           // sorted token
    int k8 = gid & 127;
    int src = perm[st];
    const float4* p = (const float4*)(x + (size_t)src * 1024 + k8 * 8);
    float4 a = p[0], b = p[1];
    unsigned r0 = (unsigned)f2bf(a.x) | ((unsigned)f2bf(a.y) << 16);
    unsigned r1 = (unsigned)f2bf(a.z) | ((unsigned)f2bf(a.w) << 16);
    unsigned r2 = (unsigned)f2bf(b.x) | ((unsigned)f2bf(b.y) << 16);
    unsigned r3 = (unsigned)f2bf(b.z) | ((unsigned)f2bf(b.w) << 16);
    *(uint4*)(xs + (size_t)st * 1024 + k8 * 8) = make_uint4(r0, r1, r2, r3);
}

// ---------------- kernel 3: W1|R1 -> bf16, transposed to [e][n=512][k=1024] ----------------
__global__ __launch_bounds__(256) void k_wcvt(const float* __restrict__ W1,
                                              const float* __restrict__ R1,
                                              unsigned short* __restrict__ wt) {
    __shared__ float tile[64][65];
    int k0 = blockIdx.x * 64;       // 0..960
    int n0 = blockIdx.y * 64;       // 0..448
    int e  = blockIdx.z;
    const float* src = (n0 < 256) ? (W1 + (size_t)e * 1024 * 256 + n0)
                                  : (R1 + (size_t)e * 1024 * 256 + (n0 - 256));
    int tid = threadIdx.x;
    int rr = tid >> 4;              // 0..15
    int cg = (tid & 15) * 4;
#pragma unroll
    for (int p = 0; p < 4; p++) {
        int kk = p * 16 + rr;
        float4 v = *(const float4*)(src + (size_t)(k0 + kk) * 256 + cg);
        tile[kk][cg] = v.x; tile[kk][cg + 1] = v.y; tile[kk][cg + 2] = v.z; tile[kk][cg + 3] = v.w;
    }
    __syncthreads();
    int nn = tid >> 3;              // 0..31
    int k8 = tid & 7;
#pragma unroll
    for (int p = 0; p < 2; p++) {
        int n = p * 32 + nn;
        unsigned w[4];
#pragma unroll
        for (int j = 0; j < 4; j++) {
            float f0 = tile[k8 * 8 + 2 * j][n];
            float f1 = tile[k8 * 8 + 2 * j + 1][n];
            w[j] = (unsigned)f2bf(f0) | ((unsigned)f2bf(f1) << 16);
        }
        *(uint4*)(wt + (size_t)(e * 512 + n0 + n) * 1024 + k0 + k8 * 8) =
            make_uint4(w[0], w[1], w[2], w[3]);
    }
}

// ---------------- kernel 4: layer-1 fused GEMM  h1 = relu(x @ [W1|R1] + [b1|rb1]) ----------------
// m93-class structure: 128x128 tile, BK=32, 4 waves each 64x64, manual staging
// (uint4 global load -> ds_write_b128).
__global__ __launch_bounds__(256) void k_gemm(const unsigned short* __restrict__ xs,
                                              const unsigned short* __restrict__ wt,
                                              const float* __restrict__ b1,
                                              const float* __restrict__ rb1,
                                              const int* __restrict__ ws_i,
                                              unsigned short* __restrict__ h1) {
    __shared__ __align__(16) short As[128 * 32];
    __shared__ __align__(16) short Bs[128 * 32];
    int c = blockIdx.x;
    int len = ws_i[(WS_CL128 >> 2) + c];
    if (len <= 0) return;
    int e    = ws_i[(WS_CE128 >> 2) + c];
    int base = ws_i[(WS_CB128 >> 2) + c];
    int n0 = blockIdx.y * 128;
    int tid = threadIdx.x;
    int wave = tid >> 6, lane = tid & 63;
    int quad = lane >> 4, lr = lane & 15;
    int wm = (wave & 1) * 64, wn = (wave >> 1) * 64;

    f32x4 acc[4][4];
#pragma unroll
    for (int i = 0; i < 4; i++)
#pragma unroll
        for (int j = 0; j < 4; j++) acc[i][j] = (f32x4){0.f, 0.f, 0.f, 0.f};

    const unsigned short* Ag = xs + (size_t)base * 1024;
    const unsigned short* Bg = wt + (size_t)(e * 512 + n0) * 1024;

    for (int kb = 0; kb < 32; kb++) {
        __syncthreads();   // LDS safe to overwrite
#pragma unroll
        for (int i = 0; i < 2; i++) {
            int g = i * 256 + tid;                 // 16B chunk id (0..511)
            int r = g >> 2, k8 = g & 3;
            uint4 va = *(const uint4*)(Ag + (size_t)r * 1024 + kb * 32 + k8 * 8);
            uint4 vb = *(const uint4*)(Bg + (size_t)r * 1024 + kb * 32 + k8 * 8);
            *(uint4*)(As + g * 8) = va;            // As[r*32 + k8*8 .. +7]
            *(uint4*)(Bs + g * 8) = vb;
        }
        __syncthreads();

        bf16x8 af[4], bfr[4];
#pragma unroll
        for (int im = 0; im < 4; im++)
            af[im] = *(const bf16x8*)(As + ((wm + im * 16 + lr) * 32 + quad * 8));
#pragma unroll
        for (int in = 0; in < 4; in++)
            bfr[in] = *(const bf16x8*)(Bs + ((wn + in * 16 + lr) * 32 + quad * 8));
#pragma unroll
        for (int im = 0; im < 4; im++)
#pragma unroll
            for (int in = 0; in < 4; in++)
                acc[im][in] = __builtin_amdgcn_mfma_f32_16x16x32_bf16(af[im], bfr[in], acc[im][in], 0, 0, 0);
    }

    // epilogue: + bias, relu, store bf16. C/D layout: col=lane&15, row=quad*4+reg.
#pragma unroll
    for (int in = 0; in < 4; in++) {
        int gcol = n0 + wn + in * 16 + lr;
        float bias = (gcol < 256) ? b1[e * 256 + gcol] : rb1[e * 256 + gcol - 256];
#pragma unroll
        for (int im = 0; im < 4; im++) {
#pragma unroll
            for (int v = 0; v < 4; v++) {
                int r = wm + im * 16 + quad * 4 + v;
                if (r < len) {
                    float val = fmaxf(acc[im][in][v] + bias, 0.f);
                    h1[(size_t)(base + r) * 512 + gcol] = f2bf(val);
                }
            }
        }
    }
}

// ---------------- kernel 5: layers 2-4 + rot layer 2 + masked scatter to output ----------------
__global__ __launch_bounds__(256) void k_tail(const unsigned short* __restrict__ h1,
                                              const int* __restrict__ ws_i,
                                              const float* __restrict__ W2, const float* __restrict__ b2,
                                              const float* __restrict__ W3, const float* __restrict__ b3,
                                              const float* __restrict__ W4, const float* __restrict__ b4,
                                              const float* __restrict__ R2, const float* __restrict__ rb2,
                                              const int* __restrict__ lengths,
                                              float* __restrict__ out) {
    __shared__ unsigned short W2u[256 * 64];   // bf16 to keep static LDS < 64 KB
    __shared__ float W3s[64 * 32];
    __shared__ float W4s[32 * 14];
    __shared__ float R2s[256 * 3];
    __shared__ float b2s[64], b3s[32], b4s[14], rb2s[3];
    __shared__ __align__(16) float h1s[4][512];
    __shared__ __align__(16) float h2s[4][64];
    __shared__ __align__(16) float h3s[4][32];

    int c = blockIdx.x;
    int len = ws_i[(WS_CL64 >> 2) + c];
    if (len <= 0) return;
    int e    = ws_i[(WS_CE64 >> 2) + c];
    int base = ws_i[(WS_CB64 >> 2) + c];
    int tid = threadIdx.x;

    // stage weights
    {
        const float4* s2 = (const float4*)(W2 + (size_t)e * 16384);
        for (int j = tid; j < 4096; j += 256) {
            float4 v = s2[j];
            unsigned p0 = (unsigned)f2bf(v.x) | ((unsigned)f2bf(v.y) << 16);
            unsigned p1 = (unsigned)f2bf(v.z) | ((unsigned)f2bf(v.w) << 16);
            *(uint2*)(W2u + j * 4) = make_uint2(p0, p1);
        }
        const float4* s3 = (const float4*)(W3 + (size_t)e * 2048);
        float4* d3 = (float4*)W3s;
        for (int j = tid; j < 512; j += 256) d3[j] = s3[j];
        // FIX (round 3): strided loop — previous `if (tid < 448)` with blockDim=256
        // left W4s[256..447] as uninitialized LDS garbage (the 2.81 absmax).
        for (int j = tid; j < 448; j += 256) W4s[j] = W4[e * 448 + j];
        const float4* sr = (const float4*)(R2 + (size_t)e * 768);
        float4* dr = (float4*)R2s;
        if (tid < 192) dr[tid] = sr[tid];
        if (tid < 64) b2s[tid] = b2[e * 64 + tid];
        if (tid < 32) b3s[tid] = b3[e * 32 + tid];
        if (tid < 14) b4s[tid] = b4[e * 14 + tid];
        if (tid < 3)  rb2s[tid] = rb2[e * 3 + tid];
    }
    __syncthreads();

    int wave = tid >> 6, lane = tid & 63;
    const int* perm = ws_i + (WS_PERM >> 2);

    for (int t = wave; t < len; t += 4) {
        int srow = base + t;
        // cooperative load of h1 row (512 bf16) into LDS as fp32
        uint4 u = *(const uint4*)(h1 + (size_t)srow * 512 + lane * 8);
        float* hr = h1s[wave];
        hr[lane * 8 + 0] = bf2f((unsigned short)(u.x & 0xffffu));
        hr[lane * 8 + 1] = bf2f((unsigned short)(u.x >> 16));
        hr[lane * 8 + 2] = bf2f((unsigned short)(u.y & 0xffffu));
        hr[lane * 8 + 3] = bf2f((unsigned short)(u.y >> 16));
        hr[lane * 8 + 4] = bf2f((unsigned short)(u.z & 0xffffu));
        hr[lane * 8 + 5] = bf2f((unsigned short)(u.z >> 16));
        hr[lane * 8 + 6] = bf2f((unsigned short)(u.w & 0xffffu));
        hr[lane * 8 + 7] = bf2f((unsigned short)(u.w >> 16));
        // layer 2: n = lane (64 outputs), K=256
        {
            int n = lane;
            float s = b2s[n];
            for (int k = 0; k < 256; k += 4) {
                float4 h4 = *(const float4*)(hr + k);
                s = fmaf(h4.x, bf2f(W2u[(k + 0) * 64 + n]), s);
                s = fmaf(h4.y, bf2f(W2u[(k + 1) * 64 + n]), s);
                s = fmaf(h4.z, bf2f(W2u[(k + 2) * 64 + n]), s);
                s = fmaf(h4.w, bf2f(W2u[(k + 3) * 64 + n]), s);
            }
            h2s[wave][n] = fmaxf(s, 0.f);
        }
        // layer 3: n = lane<32, K=64
        if (lane < 32) {
            float s = b3s[lane];
            for (int k = 0; k < 64; k += 4) {
                float4 h4 = *(const float4*)(&h2s[wave][k]);
                s = fmaf(h4.x, W3s[(k + 0) * 32 + lane], s);
                s = fmaf(h4.y, W3s[(k + 1) * 32 + lane], s);
                s = fmaf(h4.z, W3s[(k + 2) * 32 + lane], s);
                s = fmaf(h4.w, W3s[(k + 3) * 32 + lane], s);
            }
            h3s[wave][lane] = fmaxf(s, 0.f);
        }
        // layer 4 (y, 14 outputs, K=32, linear)
        float yv = 0.f;
        if (lane < 14) {
            float s = b4s[lane];
            for (int k = 0; k < 32; k += 4) {
                float4 h4 = *(const float4*)(&h3s[wave][k]);
                s = fmaf(h4.x, W4s[(k + 0) * 14 + lane], s);
                s = fmaf(h4.y, W4s[(k + 1) * 14 + lane], s);
                s = fmaf(h4.z, W4s[(k + 2) * 14 + lane], s);
                s = fmaf(h4.w, W4s[(k + 3) * 14 + lane], s);
            }
            yv = s;
        }
        // rot (3 outputs, K=256, linear): lane = p*4 + o, partials reduced over p
        int o = lane & 3, p = lane >> 2;
        float pr = 0.f;
        if (o < 3) {
#pragma unroll
            for (int j4 = 0; j4 < 4; j4++) {
                int kb = p * 16 + j4 * 4;
                float4 h4 = *(const float4*)(hr + 256 + kb);
                pr = fmaf(h4.x, R2s[(kb + 0) * 3 + o], pr);
                pr = fmaf(h4.y, R2s[(kb + 1) * 3 + o], pr);
                pr = fmaf(h4.z, R2s[(kb + 2) * 3 + o], pr);
                pr = fmaf(h4.w, R2s[(kb + 3) * 3 + o], pr);
            }
        }
        pr += __shfl_down(pr, 32, 64);
        pr += __shfl_down(pr, 16, 64);
        pr += __shfl_down(pr, 8, 64);
        pr += __shfl_down(pr, 4, 64);
        // write output (masked)
        int token = perm[srow];
        int bi = token >> 9, ni = token & 511;
        int valid = ni < lengths[bi];
        if (lane < 14) out[(size_t)token * 17 + lane] = valid ? yv : EPSV;
        if (lane < 3)  out[(size_t)token * 17 + 14 + lane] = valid ? (pr + rb2s[lane]) : EPSV;
    }
}

extern "C" void kernel_launch(void* const* d_in, const int* in_sizes, int n_in,
                              void* d_out, int out_size, void* d_ws, size_t ws_size,
                              hipStream_t stream) {
    (void)in_sizes; (void)n_in; (void)out_size; (void)ws_size;
    const float* nodes   = (const float*)d_in[0];
    const int*   sem     = (const int*)d_in[1];
    const int*   lengths = (const int*)d_in[2];
    const float* W1 = (const float*)d_in[3];
    const float* b1 = (const float*)d_in[4];
    const float* W2 = (const float*)d_in[5];
    const float* b2 = (const float*)d_in[6];
    const float* W3 = (const float*)d_in[7];
    const float* b3 = (const float*)d_in[8];
    const float* W4 = (const float*)d_in[9];
    const float* b4 = (const float*)d_in[10];
    const float* R1  = (const float*)d_in[11];
    const float* rb1 = (const float*)d_in[12];
    const float* R2  = (const float*)d_in[13];
    const float* rb2 = (const float*)d_in[14];
    float* out = (float*)d_out;

    char* ws = (char*)d_ws;
    int* ws_i = (int*)ws;
    unsigned short* xs = (unsigned short*)(ws + WS_XS);
    unsigned short* wt = (unsigned short*)(ws + WS_WT);
    unsigned short* h1 = (unsigned short*)(ws + WS_H1);

    hipLaunchKernelGGL(k_prep, dim3(1), dim3(256), 0, stream, sem, ws_i);
    hipLaunchKernelGGL(k_xgather, dim3(8192), dim3(256), 0, stream, nodes, (const int*)ws_i, xs);
    hipLaunchKernelGGL(k_wcvt, dim3(16, 8, 8), dim3(256), 0, stream, W1, R1, wt);
    hipLaunchKernelGGL(k_gemm, dim3(MAXC128, 4), dim3(256), 0, stream,
                       (const unsigned short*)xs, (const unsigned short*)wt, b1, rb1,
                       (const int*)ws_i, h1);
    hipLaunchKernelGGL(k_tail, dim3(MAXC64), dim3(256), 0, stream,
                       (const unsigned short*)h1, (const int*)ws_i,
                       W2, b2, W3, b3, W4, b4, R2, rb2, lengths, out);
}

// Round 4
// 321.243 us; speedup vs baseline: 1.3681x; 1.3681x over previous
//
#include <hip/hip_runtime.h>
#include <stdint.h>

// Problem constants
#define T_TOK 16384     // 32*512 tokens
#define NE 8            // experts
#define EPSV 1e-8f
#define MAXC128 136     // max 128-token chunks: 128 + 7 partials, rounded up
#define MAXC64  264     // max 64-token chunks: 256 + 7 partials, rounded up

// ws layout (byte offsets). Total ~59.1 MB.
#define WS_PERM   0                         // int[16384]
#define WS_CNT    65536                     // int[8]
#define WS_CUR    65600                     // int[8]
#define WS_OFFS   65664                     // int[9]
#define WS_XS     131072                    // bf16[16512][1024] (slack rows for OOB-safe tile loads)
#define WS_WT     (WS_XS + 16512*1024*2)    // bf16[8][512][1024]  (W1|R1 transposed, B^T layout)
#define WS_H1     (WS_WT + 8*512*1024*2)    // bf16[16384][512]

typedef __attribute__((ext_vector_type(8))) short bf16x8;
typedef __attribute__((ext_vector_type(4))) float f32x4;

__device__ __forceinline__ unsigned short f2bf(float f) {
    unsigned u = __float_as_uint(f);
    u += 0x7fffu + ((u >> 16) & 1u);   // RNE
    return (unsigned short)(u >> 16);
}
__device__ __forceinline__ float bf2f(unsigned short h) {
    return __uint_as_float(((unsigned)h) << 16);
}

// chunk id -> (expert, base, len) from the 9-entry prefix array. Uniform scalar loop.
__device__ __forceinline__ bool chunk_lookup(const int* __restrict__ offs, int c, int csize,
                                             int& e, int& base, int& len) {
    int acc = 0;
#pragma unroll
    for (int i = 0; i < NE; i++) {
        int s = offs[i], t = offs[i + 1];
        int cc = (t - s + csize - 1) / csize;
        if (c < acc + cc) {
            e = i;
            base = s + (c - acc) * csize;
            len = (t - base < csize) ? (t - base) : csize;
            return true;
        }
        acc += cc;
    }
    return false;
}

// ---------------- prep chain (parallelized, replaces round-3's 165us single-block k_prep) ----
__global__ __launch_bounds__(64) void k_zero(int* __restrict__ ws_i) {
    int t = threadIdx.x;
    if (t < NE) ws_i[(WS_CNT >> 2) + t] = 0;
    if (t < NE) ws_i[(WS_CUR >> 2) + t] = 0;
}

__global__ __launch_bounds__(256) void k_hist(const int* __restrict__ sem, int* __restrict__ ws_i) {
    __shared__ int cnt[NE];
    int tid = threadIdx.x, lane = tid & 63;
    if (tid < NE) cnt[tid] = 0;
    __syncthreads();
    int s = sem[blockIdx.x * 256 + tid];
#pragma unroll
    for (int e = 0; e < NE; e++) {
        unsigned long long m = __ballot(s == e);
        if (lane == e) atomicAdd(&cnt[e], (int)__popcll(m));
    }
    __syncthreads();
    if (tid < NE) atomicAdd(ws_i + (WS_CNT >> 2) + tid, cnt[tid]);
}

__global__ __launch_bounds__(64) void k_scan(int* __restrict__ ws_i) {
    if (threadIdx.x == 0) {
        int acc = 0;
        int* offs = ws_i + (WS_OFFS >> 2);
        for (int e = 0; e < NE; e++) {
            offs[e] = acc;
            ws_i[(WS_CUR >> 2) + e] = acc;
            acc += ws_i[(WS_CNT >> 2) + e];
        }
        offs[NE] = acc;
    }
}

__global__ __launch_bounds__(256) void k_scatter(const int* __restrict__ sem, int* __restrict__ ws_i) {
    int tid = threadIdx.x, lane = tid & 63;
    int i = blockIdx.x * 256 + tid;
    int s = sem[i];
    int* perm = ws_i + (WS_PERM >> 2);
#pragma unroll
    for (int e = 0; e < NE; e++) {
        unsigned long long m = __ballot(s == e);
        if (s == e) {
            int leader = (int)__builtin_ctzll(m);
            int rank = (int)__popcll(m & ((1ull << lane) - 1ull));
            int bpos = 0;
            if (lane == leader) bpos = atomicAdd(ws_i + (WS_CUR >> 2) + e, (int)__popcll(m));
            bpos = __shfl(bpos, leader, 64);
            perm[bpos + rank] = i;
        }
    }
}

// ---------------- kernel 2: gather + fp32->bf16 convert of nodes ----------------
__global__ __launch_bounds__(256) void k_xgather(const float* __restrict__ x,
                                                 const int* __restrict__ perm,
                                                 unsigned short* __restrict__ xs) {
    int gid = blockIdx.x * 256 + threadIdx.x;    // 0 .. 2097151
    int st = gid >> 7;                           // sorted token
    int k8 = gid & 127;
    int src = perm[st];
    const float4* p = (const float4*)(x + (size_t)src * 1024 + k8 * 8);
    float4 a = p[0], b = p[1];
    unsigned r0 = (unsigned)f2bf(a.x) | ((unsigned)f2bf(a.y) << 16);
    unsigned r1 = (unsigned)f2bf(a.z) | ((unsigned)f2bf(a.w) << 16);
    unsigned r2 = (unsigned)f2bf(b.x) | ((unsigned)f2bf(b.y) << 16);
    unsigned r3 = (unsigned)f2bf(b.z) | ((unsigned)f2bf(b.w) << 16);
    *(uint4*)(xs + (size_t)st * 1024 + k8 * 8) = make_uint4(r0, r1, r2, r3);
}

// ---------------- kernel 3: W1|R1 -> bf16, transposed to [e][n=512][k=1024] ----------------
__global__ __launch_bounds__(256) void k_wcvt(const float* __restrict__ W1,
                                              const float* __restrict__ R1,
                                              unsigned short* __restrict__ wt) {
    __shared__ float tile[64][65];
    int k0 = blockIdx.x * 64;       // 0..960
    int n0 = blockIdx.y * 64;       // 0..448
    int e  = blockIdx.z;
    const float* src = (n0 < 256) ? (W1 + (size_t)e * 1024 * 256 + n0)
                                  : (R1 + (size_t)e * 1024 * 256 + (n0 - 256));
    int tid = threadIdx.x;
    int rr = tid >> 4;              // 0..15
    int cg = (tid & 15) * 4;
#pragma unroll
    for (int p = 0; p < 4; p++) {
        int kk = p * 16 + rr;
        float4 v = *(const float4*)(src + (size_t)(k0 + kk) * 256 + cg);
        tile[kk][cg] = v.x; tile[kk][cg + 1] = v.y; tile[kk][cg + 2] = v.z; tile[kk][cg + 3] = v.w;
    }
    __syncthreads();
    int nn = tid >> 3;              // 0..31
    int k8 = tid & 7;
#pragma unroll
    for (int p = 0; p < 2; p++) {
        int n = p * 32 + nn;
        unsigned w[4];
#pragma unroll
        for (int j = 0; j < 4; j++) {
            float f0 = tile[k8 * 8 + 2 * j][n];
            float f1 = tile[k8 * 8 + 2 * j + 1][n];
            w[j] = (unsigned)f2bf(f0) | ((unsigned)f2bf(f1) << 16);
        }
        *(uint4*)(wt + (size_t)(e * 512 + n0 + n) * 1024 + k0 + k8 * 8) =
            make_uint4(w[0], w[1], w[2], w[3]);
    }
}

// ---------------- kernel 4: layer-1 fused GEMM  h1 = relu(x @ [W1|R1] + [b1|rb1]) ----------------
// m93-class structure: 128x128 tile, BK=32, 4 waves each 64x64, manual staging.
__global__ __launch_bounds__(256) void k_gemm(const unsigned short* __restrict__ xs,
                                              const unsigned short* __restrict__ wt,
                                              const float* __restrict__ b1,
                                              const float* __restrict__ rb1,
                                              const int* __restrict__ ws_i,
                                              unsigned short* __restrict__ h1) {
    __shared__ __align__(16) short As[128 * 32];
    __shared__ __align__(16) short Bs[128 * 32];
    int e, base, len;
    if (!chunk_lookup(ws_i + (WS_OFFS >> 2), blockIdx.x, 128, e, base, len)) return;
    int n0 = blockIdx.y * 128;
    int tid = threadIdx.x;
    int wave = tid >> 6, lane = tid & 63;
    int quad = lane >> 4, lr = lane & 15;
    int wm = (wave & 1) * 64, wn = (wave >> 1) * 64;

    f32x4 acc[4][4];
#pragma unroll
    for (int i = 0; i < 4; i++)
#pragma unroll
        for (int j = 0; j < 4; j++) acc[i][j] = (f32x4){0.f, 0.f, 0.f, 0.f};

    const unsigned short* Ag = xs + (size_t)base * 1024;
    const unsigned short* Bg = wt + (size_t)(e * 512 + n0) * 1024;

    for (int kb = 0; kb < 32; kb++) {
        __syncthreads();   // LDS safe to overwrite
#pragma unroll
        for (int i = 0; i < 2; i++) {
            int g = i * 256 + tid;                 // 16B chunk id (0..511)
            int r = g >> 2, k8 = g & 3;
            uint4 va = *(const uint4*)(Ag + (size_t)r * 1024 + kb * 32 + k8 * 8);
            uint4 vb = *(const uint4*)(Bg + (size_t)r * 1024 + kb * 32 + k8 * 8);
            *(uint4*)(As + g * 8) = va;            // As[r*32 + k8*8 .. +7]
            *(uint4*)(Bs + g * 8) = vb;
        }
        __syncthreads();

        bf16x8 af[4], bfr[4];
#pragma unroll
        for (int im = 0; im < 4; im++)
            af[im] = *(const bf16x8*)(As + ((wm + im * 16 + lr) * 32 + quad * 8));
#pragma unroll
        for (int in = 0; in < 4; in++)
            bfr[in] = *(const bf16x8*)(Bs + ((wn + in * 16 + lr) * 32 + quad * 8));
#pragma unroll
        for (int im = 0; im < 4; im++)
#pragma unroll
            for (int in = 0; in < 4; in++)
                acc[im][in] = __builtin_amdgcn_mfma_f32_16x16x32_bf16(af[im], bfr[in], acc[im][in], 0, 0, 0);
    }

    // epilogue: + bias, relu, store bf16. C/D layout: col=lane&15, row=quad*4+reg.
#pragma unroll
    for (int in = 0; in < 4; in++) {
        int gcol = n0 + wn + in * 16 + lr;
        float bias = (gcol < 256) ? b1[e * 256 + gcol] : rb1[e * 256 + gcol - 256];
#pragma unroll
        for (int im = 0; im < 4; im++) {
#pragma unroll
            for (int v = 0; v < 4; v++) {
                int r = wm + im * 16 + quad * 4 + v;
                if (r < len) {
                    float val = fmaxf(acc[im][in][v] + bias, 0.f);
                    h1[(size_t)(base + r) * 512 + gcol] = f2bf(val);
                }
            }
        }
    }
}

// ---------------- kernel 5: layers 2-4 + rot layer 2 + masked scatter to output ----------------
__global__ __launch_bounds__(256) void k_tail(const unsigned short* __restrict__ h1,
                                              const int* __restrict__ ws_i,
                                              const float* __restrict__ W2, const float* __restrict__ b2,
                                              const float* __restrict__ W3, const float* __restrict__ b3,
                                              const float* __restrict__ W4, const float* __restrict__ b4,
                                              const float* __restrict__ R2, const float* __restrict__ rb2,
                                              const int* __restrict__ lengths,
                                              float* __restrict__ out) {
    __shared__ unsigned short W2u[256 * 64];   // bf16 to keep static LDS < 64 KB
    __shared__ float W3s[64 * 32];
    __shared__ float W4s[32 * 14];
    __shared__ float R2s[256 * 3];
    __shared__ float b2s[64], b3s[32], b4s[14], rb2s[3];
    __shared__ __align__(16) float h1s[4][512];
    __shared__ __align__(16) float h2s[4][64];
    __shared__ __align__(16) float h3s[4][32];

    int e, base, len;
    if (!chunk_lookup(ws_i + (WS_OFFS >> 2), blockIdx.x, 64, e, base, len)) return;
    int tid = threadIdx.x;

    // stage weights
    {
        const float4* s2 = (const float4*)(W2 + (size_t)e * 16384);
        for (int j = tid; j < 4096; j += 256) {
            float4 v = s2[j];
            unsigned p0 = (unsigned)f2bf(v.x) | ((unsigned)f2bf(v.y) << 16);
            unsigned p1 = (unsigned)f2bf(v.z) | ((unsigned)f2bf(v.w) << 16);
            *(uint2*)(W2u + j * 4) = make_uint2(p0, p1);
        }
        const float4* s3 = (const float4*)(W3 + (size_t)e * 2048);
        float4* d3 = (float4*)W3s;
        for (int j = tid; j < 512; j += 256) d3[j] = s3[j];
        for (int j = tid; j < 448; j += 256) W4s[j] = W4[e * 448 + j];
        const float4* sr = (const float4*)(R2 + (size_t)e * 768);
        float4* dr = (float4*)R2s;
        if (tid < 192) dr[tid] = sr[tid];
        if (tid < 64) b2s[tid] = b2[e * 64 + tid];
        if (tid < 32) b3s[tid] = b3[e * 32 + tid];
        if (tid < 14) b4s[tid] = b4[e * 14 + tid];
        if (tid < 3)  rb2s[tid] = rb2[e * 3 + tid];
    }
    __syncthreads();

    int wave = tid >> 6, lane = tid & 63;
    const int* perm = ws_i + (WS_PERM >> 2);

    for (int t = wave; t < len; t += 4) {
        int srow = base + t;
        // cooperative load of h1 row (512 bf16) into LDS as fp32
        uint4 u = *(const uint4*)(h1 + (size_t)srow * 512 + lane * 8);
        float* hr = h1s[wave];
        hr[lane * 8 + 0] = bf2f((unsigned short)(u.x & 0xffffu));
        hr[lane * 8 + 1] = bf2f((unsigned short)(u.x >> 16));
        hr[lane * 8 + 2] = bf2f((unsigned short)(u.y & 0xffffu));
        hr[lane * 8 + 3] = bf2f((unsigned short)(u.y >> 16));
        hr[lane * 8 + 4] = bf2f((unsigned short)(u.z & 0xffffu));
        hr[lane * 8 + 5] = bf2f((unsigned short)(u.z >> 16));
        hr[lane * 8 + 6] = bf2f((unsigned short)(u.w & 0xffffu));
        hr[lane * 8 + 7] = bf2f((unsigned short)(u.w >> 16));
        // layer 2: n = lane (64 outputs), K=256
        {
            int n = lane;
            float s = b2s[n];
            for (int k = 0; k < 256; k += 4) {
                float4 h4 = *(const float4*)(hr + k);
                s = fmaf(h4.x, bf2f(W2u[(k + 0) * 64 + n]), s);
                s = fmaf(h4.y, bf2f(W2u[(k + 1) * 64 + n]), s);
                s = fmaf(h4.z, bf2f(W2u[(k + 2) * 64 + n]), s);
                s = fmaf(h4.w, bf2f(W2u[(k + 3) * 64 + n]), s);
            }
            h2s[wave][n] = fmaxf(s, 0.f);
        }
        // layer 3: n = lane<32, K=64
        if (lane < 32) {
            float s = b3s[lane];
            for (int k = 0; k < 64; k += 4) {
                float4 h4 = *(const float4*)(&h2s[wave][k]);
                s = fmaf(h4.x, W3s[(k + 0) * 32 + lane], s);
                s = fmaf(h4.y, W3s[(k + 1) * 32 + lane], s);
                s = fmaf(h4.z, W3s[(k + 2) * 32 + lane], s);
                s = fmaf(h4.w, W3s[(k + 3) * 32 + lane], s);
            }
            h3s[wave][lane] = fmaxf(s, 0.f);
        }
        // layer 4 (y, 14 outputs, K=32, linear)
        float yv = 0.f;
        if (lane < 14) {
            float s = b4s[lane];
            for (int k = 0; k < 32; k += 4) {
                float4 h4 = *(const float4*)(&h3s[wave][k]);
                s = fmaf(h4.x, W4s[(k + 0) * 14 + lane], s);
                s = fmaf(h4.y, W4s[(k + 1) * 14 + lane], s);
                s = fmaf(h4.z, W4s[(k + 2) * 14 + lane], s);
                s = fmaf(h4.w, W4s[(k + 3) * 14 + lane], s);
            }
            yv = s;
        }
        // rot (3 outputs, K=256, linear): lane = p*4 + o, partials reduced over p
        int o = lane & 3, p = lane >> 2;
        float pr = 0.f;
        if (o < 3) {
#pragma unroll
            for (int j4 = 0; j4 < 4; j4++) {
                int kb = p * 16 + j4 * 4;
                float4 h4 = *(const float4*)(hr + 256 + kb);
                pr = fmaf(h4.x, R2s[(kb + 0) * 3 + o], pr);
                pr = fmaf(h4.y, R2s[(kb + 1) * 3 + o], pr);
                pr = fmaf(h4.z, R2s[(kb + 2) * 3 + o], pr);
                pr = fmaf(h4.w, R2s[(kb + 3) * 3 + o], pr);
            }
        }
        pr += __shfl_down(pr, 32, 64);
        pr += __shfl_down(pr, 16, 64);
        pr += __shfl_down(pr, 8, 64);
        pr += __shfl_down(pr, 4, 64);
        // write output (masked)
        int token = perm[srow];
        int bi = token >> 9, ni = token & 511;
        int valid = ni < lengths[bi];
        if (lane < 14) out[(size_t)token * 17 + lane] = valid ? yv : EPSV;
        if (lane < 3)  out[(size_t)token * 17 + 14 + lane] = valid ? (pr + rb2s[lane]) : EPSV;
    }
}

extern "C" void kernel_launch(void* const* d_in, const int* in_sizes, int n_in,
                              void* d_out, int out_size, void* d_ws, size_t ws_size,
                              hipStream_t stream) {
    (void)in_sizes; (void)n_in; (void)out_size; (void)ws_size;
    const float* nodes   = (const float*)d_in[0];
    const int*   sem     = (const int*)d_in[1];
    const int*   lengths = (const int*)d_in[2];
    const float* W1 = (const float*)d_in[3];
    const float* b1 = (const float*)d_in[4];
    const float* W2 = (const float*)d_in[5];
    const float* b2 = (const float*)d_in[6];
    const float* W3 = (const float*)d_in[7];
    const float* b3 = (const float*)d_in[8];
    const float* W4 = (const float*)d_in[9];
    const float* b4 = (const float*)d_in[10];
    const float* R1  = (const float*)d_in[11];
    const float* rb1 = (const float*)d_in[12];
    const float* R2  = (const float*)d_in[13];
    const float* rb2 = (const float*)d_in[14];
    float* out = (float*)d_out;

    char* ws = (char*)d_ws;
    int* ws_i = (int*)ws;
    unsigned short* xs = (unsigned short*)(ws + WS_XS);
    unsigned short* wt = (unsigned short*)(ws + WS_WT);
    unsigned short* h1 = (unsigned short*)(ws + WS_H1);

    hipLaunchKernelGGL(k_zero, dim3(1), dim3(64), 0, stream, ws_i);
    hipLaunchKernelGGL(k_hist, dim3(64), dim3(256), 0, stream, sem, ws_i);
    hipLaunchKernelGGL(k_scan, dim3(1), dim3(64), 0, stream, ws_i);
    hipLaunchKernelGGL(k_scatter, dim3(64), dim3(256), 0, stream, sem, ws_i);
    hipLaunchKernelGGL(k_xgather, dim3(8192), dim3(256), 0, stream, nodes, (const int*)ws_i, xs);
    hipLaunchKernelGGL(k_wcvt, dim3(16, 8, 8), dim3(256), 0, stream, W1, R1, wt);
    hipLaunchKernelGGL(k_gemm, dim3(MAXC128, 4), dim3(256), 0, stream,
                       (const unsigned short*)xs, (const unsigned short*)wt, b1, rb1,
                       (const int*)ws_i, h1);
    hipLaunchKernelGGL(k_tail, dim3(MAXC64), dim3(256), 0, stream,
                       (const unsigned short*)h1, (const int*)ws_i,
                       W2, b2, W3, b3, W4, b4, R2, rb2, lengths, out);
}

// Round 5
// 259.908 us; speedup vs baseline: 1.6909x; 1.2360x over previous
//
#include <hip/hip_runtime.h>
#include <stdint.h>

// Problem constants
#define T_TOK 16384     // 32*512 tokens
#define NE 8            // experts
#define EPSV 1e-8f
#define MAXC128 136     // max 128-token chunks: 128 + 7 partials, rounded up
#define MAXC64  264     // max 64-token chunks: 256 + 7 partials, rounded up

// ws layout (byte offsets). Total ~56.8 MiB.
#define WS_PERM   0                         // int[16384]
#define WS_CNT    65536                     // int[8]
#define WS_CUR    65600                     // int[8]
#define WS_OFFS   65664                     // int[9]
#define WS_XS     131072                    // bf16[16512][1024] (slack rows for OOB-safe tile loads)
#define WS_WT     (WS_XS + 16512*1024*2)    // bf16[8][512][1024]  (W1|R1 transposed, B^T layout)
#define WS_H1     (WS_WT + 8*512*1024*2)    // bf16[16448][512] (64 slack rows)
#define WS_W2T    (WS_H1 + 16448*512*2)     // bf16[8][64][256]
#define WS_W3T    (WS_W2T + 8*64*256*2)     // bf16[8][32][64]
#define WS_W4T    (WS_W3T + 8*32*64*2)      // bf16[8][16][32]  (n>=14 zero)
#define WS_R2T    (WS_W4T + 8*16*32*2)      // bf16[8][16][256] (n>=3 zero)

typedef __attribute__((ext_vector_type(8))) short bf16x8;
typedef __attribute__((ext_vector_type(4))) float f32x4;

__device__ __forceinline__ unsigned short f2bf(float f) {
    unsigned u = __float_as_uint(f);
    u += 0x7fffu + ((u >> 16) & 1u);   // RNE
    return (unsigned short)(u >> 16);
}
__device__ __forceinline__ float bf2f(unsigned short h) {
    return __uint_as_float(((unsigned)h) << 16);
}

// chunk id -> (expert, base, len) from the 9-entry prefix array. Uniform scalar loop.
__device__ __forceinline__ bool chunk_lookup(const int* __restrict__ offs, int c, int csize,
                                             int& e, int& base, int& len) {
    int acc = 0;
#pragma unroll
    for (int i = 0; i < NE; i++) {
        int s = offs[i], t = offs[i + 1];
        int cc = (t - s + csize - 1) / csize;
        if (c < acc + cc) {
            e = i;
            base = s + (c - acc) * csize;
            len = (t - base < csize) ? (t - base) : csize;
            return true;
        }
        acc += cc;
    }
    return false;
}

// ---------------- prep chain ----------------
__global__ __launch_bounds__(64) void k_zero(int* __restrict__ ws_i) {
    int t = threadIdx.x;
    if (t < NE) ws_i[(WS_CNT >> 2) + t] = 0;
    if (t < NE) ws_i[(WS_CUR >> 2) + t] = 0;
}

__global__ __launch_bounds__(256) void k_hist(const int* __restrict__ sem, int* __restrict__ ws_i) {
    __shared__ int cnt[NE];
    int tid = threadIdx.x, lane = tid & 63;
    if (tid < NE) cnt[tid] = 0;
    __syncthreads();
    int s = sem[blockIdx.x * 256 + tid];
#pragma unroll
    for (int e = 0; e < NE; e++) {
        unsigned long long m = __ballot(s == e);
        if (lane == e) atomicAdd(&cnt[e], (int)__popcll(m));
    }
    __syncthreads();
    if (tid < NE) atomicAdd(ws_i + (WS_CNT >> 2) + tid, cnt[tid]);
}

__global__ __launch_bounds__(64) void k_scan(int* __restrict__ ws_i) {
    if (threadIdx.x == 0) {
        int acc = 0;
        int* offs = ws_i + (WS_OFFS >> 2);
        for (int e = 0; e < NE; e++) {
            offs[e] = acc;
            ws_i[(WS_CUR >> 2) + e] = acc;
            acc += ws_i[(WS_CNT >> 2) + e];
        }
        offs[NE] = acc;
    }
}

__global__ __launch_bounds__(256) void k_scatter(const int* __restrict__ sem, int* __restrict__ ws_i) {
    int tid = threadIdx.x, lane = tid & 63;
    int i = blockIdx.x * 256 + tid;
    int s = sem[i];
    int* perm = ws_i + (WS_PERM >> 2);
#pragma unroll
    for (int e = 0; e < NE; e++) {
        unsigned long long m = __ballot(s == e);
        if (s == e) {
            int leader = (int)__builtin_ctzll(m);
            int rank = (int)__popcll(m & ((1ull << lane) - 1ull));
            int bpos = 0;
            if (lane == leader) bpos = atomicAdd(ws_i + (WS_CUR >> 2) + e, (int)__popcll(m));
            bpos = __shfl(bpos, leader, 64);
            perm[bpos + rank] = i;
        }
    }
}

// ---------------- kernel 2: gather + fp32->bf16 convert of nodes ----------------
__global__ __launch_bounds__(256) void k_xgather(const float* __restrict__ x,
                                                 const int* __restrict__ perm,
                                                 unsigned short* __restrict__ xs) {
    int gid = blockIdx.x * 256 + threadIdx.x;    // 0 .. 2097151
    int st = gid >> 7;                           // sorted token
    int k8 = gid & 127;
    int src = perm[st];
    const float4* p = (const float4*)(x + (size_t)src * 1024 + k8 * 8);
    float4 a = p[0], b = p[1];
    unsigned r0 = (unsigned)f2bf(a.x) | ((unsigned)f2bf(a.y) << 16);
    unsigned r1 = (unsigned)f2bf(a.z) | ((unsigned)f2bf(a.w) << 16);
    unsigned r2 = (unsigned)f2bf(b.x) | ((unsigned)f2bf(b.y) << 16);
    unsigned r3 = (unsigned)f2bf(b.z) | ((unsigned)f2bf(b.w) << 16);
    *(uint4*)(xs + (size_t)st * 1024 + k8 * 8) = make_uint4(r0, r1, r2, r3);
}

// ---------------- kernel 3: W1|R1 -> bf16, transposed to [e][n=512][k=1024] ----------------
__global__ __launch_bounds__(256) void k_wcvt(const float* __restrict__ W1,
                                              const float* __restrict__ R1,
                                              unsigned short* __restrict__ wt) {
    __shared__ float tile[64][65];
    int k0 = blockIdx.x * 64;       // 0..960
    int n0 = blockIdx.y * 64;       // 0..448
    int e  = blockIdx.z;
    const float* src = (n0 < 256) ? (W1 + (size_t)e * 1024 * 256 + n0)
                                  : (R1 + (size_t)e * 1024 * 256 + (n0 - 256));
    int tid = threadIdx.x;
    int rr = tid >> 4;              // 0..15
    int cg = (tid & 15) * 4;
#pragma unroll
    for (int p = 0; p < 4; p++) {
        int kk = p * 16 + rr;
        float4 v = *(const float4*)(src + (size_t)(k0 + kk) * 256 + cg);
        tile[kk][cg] = v.x; tile[kk][cg + 1] = v.y; tile[kk][cg + 2] = v.z; tile[kk][cg + 3] = v.w;
    }
    __syncthreads();
    int nn = tid >> 3;              // 0..31
    int k8 = tid & 7;
#pragma unroll
    for (int p = 0; p < 2; p++) {
        int n = p * 32 + nn;
        unsigned w[4];
#pragma unroll
        for (int j = 0; j < 4; j++) {
            float f0 = tile[k8 * 8 + 2 * j][n];
            float f1 = tile[k8 * 8 + 2 * j + 1][n];
            w[j] = (unsigned)f2bf(f0) | ((unsigned)f2bf(f1) << 16);
        }
        *(uint4*)(wt + (size_t)(e * 512 + n0 + n) * 1024 + k0 + k8 * 8) =
            make_uint4(w[0], w[1], w[2], w[3]);
    }
}

// ---------------- kernel 3b: tail weights -> bf16 B^T tables ----------------
__global__ __launch_bounds__(256) void k_wcvt2(const float* __restrict__ W2,
                                               const float* __restrict__ W3,
                                               const float* __restrict__ W4,
                                               const float* __restrict__ R2,
                                               unsigned short* __restrict__ w2t,
                                               unsigned short* __restrict__ w3t,
                                               unsigned short* __restrict__ w4t,
                                               unsigned short* __restrict__ r2t) {
    int e = blockIdx.x, t = threadIdx.x;
    for (int idx = t; idx < 64 * 256; idx += 256) {
        int k = idx & 255, n = idx >> 8;
        w2t[(size_t)(e * 64 + n) * 256 + k] = f2bf(W2[(size_t)e * 16384 + k * 64 + n]);
    }
    for (int idx = t; idx < 32 * 64; idx += 256) {
        int k = idx & 63, n = idx >> 6;
        w3t[(size_t)(e * 32 + n) * 64 + k] = f2bf(W3[(size_t)e * 2048 + k * 32 + n]);
    }
    for (int idx = t; idx < 16 * 32; idx += 256) {
        int k = idx & 31, n = idx >> 5;
        w4t[(size_t)(e * 16 + n) * 32 + k] = (n < 14) ? f2bf(W4[(size_t)e * 448 + k * 14 + n])
                                                      : (unsigned short)0;
    }
    for (int idx = t; idx < 16 * 256; idx += 256) {
        int k = idx & 255, n = idx >> 8;
        r2t[(size_t)(e * 16 + n) * 256 + k] = (n < 3) ? f2bf(R2[(size_t)e * 768 + k * 3 + n])
                                                      : (unsigned short)0;
    }
}

// ---------------- kernel 4: layer-1 fused GEMM  h1 = relu(x @ [W1|R1] + [b1|rb1]) ----------------
// m93-class structure: 128x128 tile, BK=32, 4 waves each 64x64, manual staging.
__global__ __launch_bounds__(256) void k_gemm(const unsigned short* __restrict__ xs,
                                              const unsigned short* __restrict__ wt,
                                              const float* __restrict__ b1,
                                              const float* __restrict__ rb1,
                                              const int* __restrict__ ws_i,
                                              unsigned short* __restrict__ h1) {
    __shared__ __align__(16) short As[128 * 32];
    __shared__ __align__(16) short Bs[128 * 32];
    int e, base, len;
    if (!chunk_lookup(ws_i + (WS_OFFS >> 2), blockIdx.x, 128, e, base, len)) return;
    int n0 = blockIdx.y * 128;
    int tid = threadIdx.x;
    int wave = tid >> 6, lane = tid & 63;
    int quad = lane >> 4, lr = lane & 15;
    int wm = (wave & 1) * 64, wn = (wave >> 1) * 64;

    f32x4 acc[4][4];
#pragma unroll
    for (int i = 0; i < 4; i++)
#pragma unroll
        for (int j = 0; j < 4; j++) acc[i][j] = (f32x4){0.f, 0.f, 0.f, 0.f};

    const unsigned short* Ag = xs + (size_t)base * 1024;
    const unsigned short* Bg = wt + (size_t)(e * 512 + n0) * 1024;

    for (int kb = 0; kb < 32; kb++) {
        __syncthreads();   // LDS safe to overwrite
#pragma unroll
        for (int i = 0; i < 2; i++) {
            int g = i * 256 + tid;                 // 16B chunk id (0..511)
            int r = g >> 2, k8 = g & 3;
            uint4 va = *(const uint4*)(Ag + (size_t)r * 1024 + kb * 32 + k8 * 8);
            uint4 vb = *(const uint4*)(Bg + (size_t)r * 1024 + kb * 32 + k8 * 8);
            *(uint4*)(As + g * 8) = va;            // As[r*32 + k8*8 .. +7]
            *(uint4*)(Bs + g * 8) = vb;
        }
        __syncthreads();

        bf16x8 af[4], bfr[4];
#pragma unroll
        for (int im = 0; im < 4; im++)
            af[im] = *(const bf16x8*)(As + ((wm + im * 16 + lr) * 32 + quad * 8));
#pragma unroll
        for (int in = 0; in < 4; in++)
            bfr[in] = *(const bf16x8*)(Bs + ((wn + in * 16 + lr) * 32 + quad * 8));
#pragma unroll
        for (int im = 0; im < 4; im++)
#pragma unroll
            for (int in = 0; in < 4; in++)
                acc[im][in] = __builtin_amdgcn_mfma_f32_16x16x32_bf16(af[im], bfr[in], acc[im][in], 0, 0, 0);
    }

    // epilogue: + bias, relu, store bf16. C/D layout: col=lane&15, row=quad*4+reg.
#pragma unroll
    for (int in = 0; in < 4; in++) {
        int gcol = n0 + wn + in * 16 + lr;
        float bias = (gcol < 256) ? b1[e * 256 + gcol] : rb1[e * 256 + gcol - 256];
#pragma unroll
        for (int im = 0; im < 4; im++) {
#pragma unroll
            for (int v = 0; v < 4; v++) {
                int r = wm + im * 16 + quad * 4 + v;
                if (r < len) {
                    float val = fmaxf(acc[im][in][v] + bias, 0.f);
                    h1[(size_t)(base + r) * 512 + gcol] = f2bf(val);
                }
            }
        }
    }
}

// ---------------- kernel 5: MFMA tail — layers 2-4 + rot + masked scatter ----------------
// 4 waves/block; wave w owns tokens [16w,16w+16) of its 64-token chunk. No barriers:
// each wave writes and reads only its own h2s/h3s rows. Biases folded into MFMA C-init.
__global__ __launch_bounds__(256) void k_tail(const unsigned short* __restrict__ h1,
                                              const int* __restrict__ ws_i,
                                              const unsigned short* __restrict__ w2t,
                                              const unsigned short* __restrict__ w3t,
                                              const unsigned short* __restrict__ w4t,
                                              const unsigned short* __restrict__ r2t,
                                              const float* __restrict__ b2,
                                              const float* __restrict__ b3,
                                              const float* __restrict__ b4,
                                              const float* __restrict__ rb2,
                                              const int* __restrict__ lengths,
                                              float* __restrict__ out) {
    __shared__ __align__(16) unsigned short h2s[4][16][64];
    __shared__ __align__(16) unsigned short h3s[4][16][32];

    int e, base, len;
    if (!chunk_lookup(ws_i + (WS_OFFS >> 2), blockIdx.x, 64, e, base, len)) return;
    int tid = threadIdx.x, wave = tid >> 6, lane = tid & 63;
    int quad = lane >> 4, lr = lane & 15;
    int m0 = wave * 16;

    const unsigned short* Ap = h1 + (size_t)(base + m0) * 512;

    // layer2 (M=16,N=64,K=256) + rot (M=16,N=3pad16,K=256), A from global h1
    f32x4 acc2[4];
#pragma unroll
    for (int t = 0; t < 4; t++) {
        float bb = b2[e * 64 + t * 16 + lr];
        acc2[t] = (f32x4){bb, bb, bb, bb};
    }
    f32x4 accr;
    { float bb = (lr < 3) ? rb2[e * 3 + lr] : 0.f; accr = (f32x4){bb, bb, bb, bb}; }

    const unsigned short* W2e = w2t + (size_t)e * 64 * 256;
    const unsigned short* R2e = r2t + (size_t)e * 16 * 256;
#pragma unroll
    for (int kk = 0; kk < 8; kk++) {
        int k0 = kk * 32;
        bf16x8 a = *(const bf16x8*)(Ap + lr * 512 + k0 + quad * 8);
#pragma unroll
        for (int t = 0; t < 4; t++) {
            bf16x8 b = *(const bf16x8*)(W2e + (t * 16 + lr) * 256 + k0 + quad * 8);
            acc2[t] = __builtin_amdgcn_mfma_f32_16x16x32_bf16(a, b, acc2[t], 0, 0, 0);
        }
        bf16x8 ar = *(const bf16x8*)(Ap + lr * 512 + 256 + k0 + quad * 8);
        bf16x8 br = *(const bf16x8*)(R2e + lr * 256 + k0 + quad * 8);
        accr = __builtin_amdgcn_mfma_f32_16x16x32_bf16(ar, br, accr, 0, 0, 0);
    }
    // h2 = relu -> LDS bf16 (C layout: row=quad*4+v, col=lr per tile)
#pragma unroll
    for (int t = 0; t < 4; t++)
#pragma unroll
        for (int v = 0; v < 4; v++)
            h2s[wave][quad * 4 + v][t * 16 + lr] = f2bf(fmaxf(acc2[t][v], 0.f));

    // layer3 (M=16,N=32,K=64)
    f32x4 acc3[2];
#pragma unroll
    for (int t = 0; t < 2; t++) {
        float bb = b3[e * 32 + t * 16 + lr];
        acc3[t] = (f32x4){bb, bb, bb, bb};
    }
    const unsigned short* W3e = w3t + (size_t)e * 32 * 64;
#pragma unroll
    for (int kk = 0; kk < 2; kk++) {
        int k0 = kk * 32;
        bf16x8 a = *(const bf16x8*)(&h2s[wave][lr][k0 + quad * 8]);
#pragma unroll
        for (int t = 0; t < 2; t++) {
            bf16x8 b = *(const bf16x8*)(W3e + (t * 16 + lr) * 64 + k0 + quad * 8);
            acc3[t] = __builtin_amdgcn_mfma_f32_16x16x32_bf16(a, b, acc3[t], 0, 0, 0);
        }
    }
#pragma unroll
    for (int t = 0; t < 2; t++)
#pragma unroll
        for (int v = 0; v < 4; v++)
            h3s[wave][quad * 4 + v][t * 16 + lr] = f2bf(fmaxf(acc3[t][v], 0.f));

    // layer4 (M=16,N=14pad16,K=32): one MFMA
    f32x4 acc4;
    { float bb = (lr < 14) ? b4[e * 14 + lr] : 0.f; acc4 = (f32x4){bb, bb, bb, bb}; }
    {
        bf16x8 a = *(const bf16x8*)(&h3s[wave][lr][quad * 8]);
        bf16x8 b = *(const bf16x8*)(w4t + ((size_t)e * 16 + lr) * 32 + quad * 8);
        acc4 = __builtin_amdgcn_mfma_f32_16x16x32_bf16(a, b, acc4, 0, 0, 0);
    }

    // stores (masked): token row = quad*4+v
    const int* perm = ws_i + (WS_PERM >> 2);
#pragma unroll
    for (int v = 0; v < 4; v++) {
        int t = m0 + quad * 4 + v;
        if (t < len) {
            int token = perm[base + t];
            int bi = token >> 9, ni = token & 511;
            int valid = ni < lengths[bi];
            if (lr < 14) out[(size_t)token * 17 + lr] = valid ? acc4[v] : EPSV;
            if (lr < 3)  out[(size_t)token * 17 + 14 + lr] = valid ? accr[v] : EPSV;
        }
    }
}

extern "C" void kernel_launch(void* const* d_in, const int* in_sizes, int n_in,
                              void* d_out, int out_size, void* d_ws, size_t ws_size,
                              hipStream_t stream) {
    (void)in_sizes; (void)n_in; (void)out_size; (void)ws_size;
    const float* nodes   = (const float*)d_in[0];
    const int*   sem     = (const int*)d_in[1];
    const int*   lengths = (const int*)d_in[2];
    const float* W1 = (const float*)d_in[3];
    const float* b1 = (const float*)d_in[4];
    const float* W2 = (const float*)d_in[5];
    const float* b2 = (const float*)d_in[6];
    const float* W3 = (const float*)d_in[7];
    const float* b3 = (const float*)d_in[8];
    const float* W4 = (const float*)d_in[9];
    const float* b4 = (const float*)d_in[10];
    const float* R1  = (const float*)d_in[11];
    const float* rb1 = (const float*)d_in[12];
    const float* R2  = (const float*)d_in[13];
    const float* rb2 = (const float*)d_in[14];
    float* out = (float*)d_out;

    char* ws = (char*)d_ws;
    int* ws_i = (int*)ws;
    unsigned short* xs  = (unsigned short*)(ws + WS_XS);
    unsigned short* wt  = (unsigned short*)(ws + WS_WT);
    unsigned short* h1  = (unsigned short*)(ws + WS_H1);
    unsigned short* w2t = (unsigned short*)(ws + WS_W2T);
    unsigned short* w3t = (unsigned short*)(ws + WS_W3T);
    unsigned short* w4t = (unsigned short*)(ws + WS_W4T);
    unsigned short* r2t = (unsigned short*)(ws + WS_R2T);

    hipLaunchKernelGGL(k_zero, dim3(1), dim3(64), 0, stream, ws_i);
    hipLaunchKernelGGL(k_hist, dim3(64), dim3(256), 0, stream, sem, ws_i);
    hipLaunchKernelGGL(k_scan, dim3(1), dim3(64), 0, stream, ws_i);
    hipLaunchKernelGGL(k_scatter, dim3(64), dim3(256), 0, stream, sem, ws_i);
    hipLaunchKernelGGL(k_xgather, dim3(8192), dim3(256), 0, stream, nodes, (const int*)ws_i, xs);
    hipLaunchKernelGGL(k_wcvt, dim3(16, 8, 8), dim3(256), 0, stream, W1, R1, wt);
    hipLaunchKernelGGL(k_wcvt2, dim3(8), dim3(256), 0, stream, W2, W3, W4, R2, w2t, w3t, w4t, r2t);
    hipLaunchKernelGGL(k_gemm, dim3(MAXC128, 4), dim3(256), 0, stream,
                       (const unsigned short*)xs, (const unsigned short*)wt, b1, rb1,
                       (const int*)ws_i, h1);
    hipLaunchKernelGGL(k_tail, dim3(MAXC64), dim3(256), 0, stream,
                       (const unsigned short*)h1, (const int*)ws_i,
                       (const unsigned short*)w2t, (const unsigned short*)w3t,
                       (const unsigned short*)w4t, (const unsigned short*)r2t,
                       b2, b3, b4, rb2, lengths, out);
}

// Round 6
// 235.980 us; speedup vs baseline: 1.8624x; 1.1014x over previous
//
#include <hip/hip_runtime.h>
#include <stdint.h>

// Problem constants
#define T_TOK 16384     // 32*512 tokens
#define NE 8            // experts
#define EPSV 1e-8f
#define MAXC128 136     // max 128-token chunks: 128 + 7 partials, rounded up
#define MAXC64  264     // max 64-token chunks: 256 + 7 partials, rounded up

// ws layout (byte offsets). Total ~56.8 MiB.
#define WS_PERM   0                         // int[16384]
#define WS_CNT    65536                     // int[8]
#define WS_CUR    65600                     // int[8]
#define WS_OFFS   65664                     // int[9]
#define WS_XS     131072                    // bf16[16512][1024] (slack rows for OOB-safe tile loads)
#define WS_WT     (WS_XS + 16512*1024*2)    // bf16[8][512][1024]  (W1|R1 transposed, B^T layout)
#define WS_H1     (WS_WT + 8*512*1024*2)    // bf16[16448][512] (64 slack rows)
#define WS_W2T    (WS_H1 + 16448*512*2)     // bf16[8][64][256]
#define WS_W3T    (WS_W2T + 8*64*256*2)     // bf16[8][32][64]
#define WS_W4T    (WS_W3T + 8*32*64*2)      // bf16[8][16][32]  (n>=14 zero)
#define WS_R2T    (WS_W4T + 8*16*32*2)      // bf16[8][16][256] (n>=3 zero)

typedef __attribute__((ext_vector_type(8))) short bf16x8;
typedef __attribute__((ext_vector_type(4))) float f32x4;

__device__ __forceinline__ unsigned short f2bf(float f) {
    unsigned u = __float_as_uint(f);
    u += 0x7fffu + ((u >> 16) & 1u);   // RNE
    return (unsigned short)(u >> 16);
}
__device__ __forceinline__ float bf2f(unsigned short h) {
    return __uint_as_float(((unsigned)h) << 16);
}

// async global->LDS, 16B per lane. LDS dest = wave-uniform base + lane*16.
// NOTE: LDS pointer must be converted via ADDRSPACECAST (pointer-type cast),
// NOT integer truncation — (unsigned)(uintptr_t) of a generic LDS pointer is
// garbage (round-1 corruption root cause).
__device__ __forceinline__ void gl_lds16(const void* g, void* l) {
    __builtin_amdgcn_global_load_lds(
        (const __attribute__((address_space(1))) void*)g,
        (__attribute__((address_space(3))) void*)l,
        16, 0, 0);
}

// chunk id -> (expert, base, len) from the 9-entry prefix array. Uniform scalar loop.
__device__ __forceinline__ bool chunk_lookup(const int* __restrict__ offs, int c, int csize,
                                             int& e, int& base, int& len) {
    int acc = 0;
#pragma unroll
    for (int i = 0; i < NE; i++) {
        int s = offs[i], t = offs[i + 1];
        int cc = (t - s + csize - 1) / csize;
        if (c < acc + cc) {
            e = i;
            base = s + (c - acc) * csize;
            len = (t - base < csize) ? (t - base) : csize;
            return true;
        }
        acc += cc;
    }
    return false;
}

// ---------------- prep chain ----------------
__global__ __launch_bounds__(64) void k_zero(int* __restrict__ ws_i) {
    int t = threadIdx.x;
    if (t < NE) ws_i[(WS_CNT >> 2) + t] = 0;
    if (t < NE) ws_i[(WS_CUR >> 2) + t] = 0;
}

__global__ __launch_bounds__(256) void k_hist(const int* __restrict__ sem, int* __restrict__ ws_i) {
    __shared__ int cnt[NE];
    int tid = threadIdx.x, lane = tid & 63;
    if (tid < NE) cnt[tid] = 0;
    __syncthreads();
    int s = sem[blockIdx.x * 256 + tid];
#pragma unroll
    for (int e = 0; e < NE; e++) {
        unsigned long long m = __ballot(s == e);
        if (lane == e) atomicAdd(&cnt[e], (int)__popcll(m));
    }
    __syncthreads();
    if (tid < NE) atomicAdd(ws_i + (WS_CNT >> 2) + tid, cnt[tid]);
}

__global__ __launch_bounds__(64) void k_scan(int* __restrict__ ws_i) {
    if (threadIdx.x == 0) {
        int acc = 0;
        int* offs = ws_i + (WS_OFFS >> 2);
        for (int e = 0; e < NE; e++) {
            offs[e] = acc;
            ws_i[(WS_CUR >> 2) + e] = acc;
            acc += ws_i[(WS_CNT >> 2) + e];
        }
        offs[NE] = acc;
    }
}

__global__ __launch_bounds__(256) void k_scatter(const int* __restrict__ sem, int* __restrict__ ws_i) {
    int tid = threadIdx.x, lane = tid & 63;
    int i = blockIdx.x * 256 + tid;
    int s = sem[i];
    int* perm = ws_i + (WS_PERM >> 2);
#pragma unroll
    for (int e = 0; e < NE; e++) {
        unsigned long long m = __ballot(s == e);
        if (s == e) {
            int leader = (int)__builtin_ctzll(m);
            int rank = (int)__popcll(m & ((1ull << lane) - 1ull));
            int bpos = 0;
            if (lane == leader) bpos = atomicAdd(ws_i + (WS_CUR >> 2) + e, (int)__popcll(m));
            bpos = __shfl(bpos, leader, 64);
            perm[bpos + rank] = i;
        }
    }
}

// ---------------- kernel 2: gather + fp32->bf16 convert of nodes ----------------
__global__ __launch_bounds__(256) void k_xgather(const float* __restrict__ x,
                                                 const int* __restrict__ perm,
                                                 unsigned short* __restrict__ xs) {
    int gid = blockIdx.x * 256 + threadIdx.x;    // 0 .. 2097151
    int st = gid >> 7;                           // sorted token
    int k8 = gid & 127;
    int src = perm[st];
    const float4* p = (const float4*)(x + (size_t)src * 1024 + k8 * 8);
    float4 a = p[0], b = p[1];
    unsigned r0 = (unsigned)f2bf(a.x) | ((unsigned)f2bf(a.y) << 16);
    unsigned r1 = (unsigned)f2bf(a.z) | ((unsigned)f2bf(a.w) << 16);
    unsigned r2 = (unsigned)f2bf(b.x) | ((unsigned)f2bf(b.y) << 16);
    unsigned r3 = (unsigned)f2bf(b.z) | ((unsigned)f2bf(b.w) << 16);
    *(uint4*)(xs + (size_t)st * 1024 + k8 * 8) = make_uint4(r0, r1, r2, r3);
}

// ---------------- kernel 3: W1|R1 -> bf16, transposed to [e][n=512][k=1024] ----------------
__global__ __launch_bounds__(256) void k_wcvt(const float* __restrict__ W1,
                                              const float* __restrict__ R1,
                                              unsigned short* __restrict__ wt) {
    __shared__ float tile[64][65];
    int k0 = blockIdx.x * 64;       // 0..960
    int n0 = blockIdx.y * 64;       // 0..448
    int e  = blockIdx.z;
    const float* src = (n0 < 256) ? (W1 + (size_t)e * 1024 * 256 + n0)
                                  : (R1 + (size_t)e * 1024 * 256 + (n0 - 256));
    int tid = threadIdx.x;
    int rr = tid >> 4;              // 0..15
    int cg = (tid & 15) * 4;
#pragma unroll
    for (int p = 0; p < 4; p++) {
        int kk = p * 16 + rr;
        float4 v = *(const float4*)(src + (size_t)(k0 + kk) * 256 + cg);
        tile[kk][cg] = v.x; tile[kk][cg + 1] = v.y; tile[kk][cg + 2] = v.z; tile[kk][cg + 3] = v.w;
    }
    __syncthreads();
    int nn = tid >> 3;              // 0..31
    int k8 = tid & 7;
#pragma unroll
    for (int p = 0; p < 2; p++) {
        int n = p * 32 + nn;
        unsigned w[4];
#pragma unroll
        for (int j = 0; j < 4; j++) {
            float f0 = tile[k8 * 8 + 2 * j][n];
            float f1 = tile[k8 * 8 + 2 * j + 1][n];
            w[j] = (unsigned)f2bf(f0) | ((unsigned)f2bf(f1) << 16);
        }
        *(uint4*)(wt + (size_t)(e * 512 + n0 + n) * 1024 + k0 + k8 * 8) =
            make_uint4(w[0], w[1], w[2], w[3]);
    }
}

// ---------------- kernel 3b: tail weights -> bf16 B^T tables ----------------
__global__ __launch_bounds__(256) void k_wcvt2(const float* __restrict__ W2,
                                               const float* __restrict__ W3,
                                               const float* __restrict__ W4,
                                               const float* __restrict__ R2,
                                               unsigned short* __restrict__ w2t,
                                               unsigned short* __restrict__ w3t,
                                               unsigned short* __restrict__ w4t,
                                               unsigned short* __restrict__ r2t) {
    int e = blockIdx.x, t = threadIdx.x;
    for (int idx = t; idx < 64 * 256; idx += 256) {
        int k = idx & 255, n = idx >> 8;
        w2t[(size_t)(e * 64 + n) * 256 + k] = f2bf(W2[(size_t)e * 16384 + k * 64 + n]);
    }
    for (int idx = t; idx < 32 * 64; idx += 256) {
        int k = idx & 63, n = idx >> 6;
        w3t[(size_t)(e * 32 + n) * 64 + k] = f2bf(W3[(size_t)e * 2048 + k * 32 + n]);
    }
    for (int idx = t; idx < 16 * 32; idx += 256) {
        int k = idx & 31, n = idx >> 5;
        w4t[(size_t)(e * 16 + n) * 32 + k] = (n < 14) ? f2bf(W4[(size_t)e * 448 + k * 14 + n])
                                                      : (unsigned short)0;
    }
    for (int idx = t; idx < 16 * 256; idx += 256) {
        int k = idx & 255, n = idx >> 8;
        r2t[(size_t)(e * 16 + n) * 256 + k] = (n < 3) ? f2bf(R2[(size_t)e * 768 + k * 3 + n])
                                                      : (unsigned short)0;
    }
}

// ---------------- kernel 4: layer-1 fused GEMM  h1 = relu(x @ [W1|R1] + [b1|rb1]) ----------------
// m97 structure: 128x128 tile, BK=32, 4 waves each 64x64, global_load_lds width-16 staging.
__global__ __launch_bounds__(256) void k_gemm(const unsigned short* __restrict__ xs,
                                              const unsigned short* __restrict__ wt,
                                              const float* __restrict__ b1,
                                              const float* __restrict__ rb1,
                                              const int* __restrict__ ws_i,
                                              unsigned short* __restrict__ h1) {
    __shared__ __align__(16) short As[128 * 32];
    __shared__ __align__(16) short Bs[128 * 32];
    int e, base, len;
    if (!chunk_lookup(ws_i + (WS_OFFS >> 2), blockIdx.x, 128, e, base, len)) return;
    int n0 = blockIdx.y * 128;
    int tid = threadIdx.x;
    int wave = tid >> 6, lane = tid & 63;
    int quad = lane >> 4, lr = lane & 15;
    int wm = (wave & 1) * 64, wn = (wave >> 1) * 64;

    f32x4 acc[4][4];
#pragma unroll
    for (int i = 0; i < 4; i++)
#pragma unroll
        for (int j = 0; j < 4; j++) acc[i][j] = (f32x4){0.f, 0.f, 0.f, 0.f};

    const unsigned short* Ag = xs + (size_t)base * 1024;
    const unsigned short* Bg = wt + (size_t)(e * 512 + n0) * 1024;

    for (int kb = 0; kb < 32; kb++) {
        __syncthreads();   // LDS safe to overwrite
#pragma unroll
        for (int i = 0; i < 2; i++) {
            int g = i * 256 + wave * 64 + lane;    // 16B chunk id (0..511)
            int r = g >> 2, k8 = g & 3;
            // LDS dest: wave-uniform base + lane*16 (g = base16 + lane exactly)
            gl_lds16(Ag + (size_t)r * 1024 + kb * 32 + k8 * 8,
                     As + (size_t)(i * 256 + wave * 64) * 8);
            gl_lds16(Bg + (size_t)r * 1024 + kb * 32 + k8 * 8,
                     Bs + (size_t)(i * 256 + wave * 64) * 8);
        }
        __syncthreads();   // compiler drains vmcnt before barrier -> DMA complete

        bf16x8 af[4], bfr[4];
#pragma unroll
        for (int im = 0; im < 4; im++)
            af[im] = *(const bf16x8*)(As + ((wm + im * 16 + lr) * 32 + quad * 8));
#pragma unroll
        for (int in = 0; in < 4; in++)
            bfr[in] = *(const bf16x8*)(Bs + ((wn + in * 16 + lr) * 32 + quad * 8));
#pragma unroll
        for (int im = 0; im < 4; im++)
#pragma unroll
            for (int in = 0; in < 4; in++)
                acc[im][in] = __builtin_amdgcn_mfma_f32_16x16x32_bf16(af[im], bfr[in], acc[im][in], 0, 0, 0);
    }

    // epilogue: + bias, relu, store bf16. C/D layout: col=lane&15, row=quad*4+reg.
#pragma unroll
    for (int in = 0; in < 4; in++) {
        int gcol = n0 + wn + in * 16 + lr;
        float bias = (gcol < 256) ? b1[e * 256 + gcol] : rb1[e * 256 + gcol - 256];
#pragma unroll
        for (int im = 0; im < 4; im++) {
#pragma unroll
            for (int v = 0; v < 4; v++) {
                int r = wm + im * 16 + quad * 4 + v;
                if (r < len) {
                    float val = fmaxf(acc[im][in][v] + bias, 0.f);
                    h1[(size_t)(base + r) * 512 + gcol] = f2bf(val);
                }
            }
        }
    }
}

// ---------------- kernel 5: MFMA tail — layers 2-4 + rot + masked scatter ----------------
// 4 waves/block; wave w owns tokens [16w,16w+16) of its 64-token chunk. No barriers:
// each wave writes and reads only its own h2s/h3s rows. Biases folded into MFMA C-init.
__global__ __launch_bounds__(256) void k_tail(const unsigned short* __restrict__ h1,
                                              const int* __restrict__ ws_i,
                                              const unsigned short* __restrict__ w2t,
                                              const unsigned short* __restrict__ w3t,
                                              const unsigned short* __restrict__ w4t,
                                              const unsigned short* __restrict__ r2t,
                                              const float* __restrict__ b2,
                                              const float* __restrict__ b3,
                                              const float* __restrict__ b4,
                                              const float* __restrict__ rb2,
                                              const int* __restrict__ lengths,
                                              float* __restrict__ out) {
    __shared__ __align__(16) unsigned short h2s[4][16][64];
    __shared__ __align__(16) unsigned short h3s[4][16][32];

    int e, base, len;
    if (!chunk_lookup(ws_i + (WS_OFFS >> 2), blockIdx.x, 64, e, base, len)) return;
    int tid = threadIdx.x, wave = tid >> 6, lane = tid & 63;
    int quad = lane >> 4, lr = lane & 15;
    int m0 = wave * 16;

    const unsigned short* Ap = h1 + (size_t)(base + m0) * 512;

    // layer2 (M=16,N=64,K=256) + rot (M=16,N=3pad16,K=256), A from global h1
    f32x4 acc2[4];
#pragma unroll
    for (int t = 0; t < 4; t++) {
        float bb = b2[e * 64 + t * 16 + lr];
        acc2[t] = (f32x4){bb, bb, bb, bb};
    }
    f32x4 accr;
    { float bb = (lr < 3) ? rb2[e * 3 + lr] : 0.f; accr = (f32x4){bb, bb, bb, bb}; }

    const unsigned short* W2e = w2t + (size_t)e * 64 * 256;
    const unsigned short* R2e = r2t + (size_t)e * 16 * 256;
#pragma unroll
    for (int kk = 0; kk < 8; kk++) {
        int k0 = kk * 32;
        bf16x8 a = *(const bf16x8*)(Ap + lr * 512 + k0 + quad * 8);
#pragma unroll
        for (int t = 0; t < 4; t++) {
            bf16x8 b = *(const bf16x8*)(W2e + (t * 16 + lr) * 256 + k0 + quad * 8);
            acc2[t] = __builtin_amdgcn_mfma_f32_16x16x32_bf16(a, b, acc2[t], 0, 0, 0);
        }
        bf16x8 ar = *(const bf16x8*)(Ap + lr * 512 + 256 + k0 + quad * 8);
        bf16x8 br = *(const bf16x8*)(R2e + lr * 256 + k0 + quad * 8);
        accr = __builtin_amdgcn_mfma_f32_16x16x32_bf16(ar, br, accr, 0, 0, 0);
    }
    // h2 = relu -> LDS bf16 (C layout: row=quad*4+v, col=lr per tile)
#pragma unroll
    for (int t = 0; t < 4; t++)
#pragma unroll
        for (int v = 0; v < 4; v++)
            h2s[wave][quad * 4 + v][t * 16 + lr] = f2bf(fmaxf(acc2[t][v], 0.f));

    // layer3 (M=16,N=32,K=64)
    f32x4 acc3[2];
#pragma unroll
    for (int t = 0; t < 2; t++) {
        float bb = b3[e * 32 + t * 16 + lr];
        acc3[t] = (f32x4){bb, bb, bb, bb};
    }
    const unsigned short* W3e = w3t + (size_t)e * 32 * 64;
#pragma unroll
    for (int kk = 0; kk < 2; kk++) {
        int k0 = kk * 32;
        bf16x8 a = *(const bf16x8*)(&h2s[wave][lr][k0 + quad * 8]);
#pragma unroll
        for (int t = 0; t < 2; t++) {
            bf16x8 b = *(const bf16x8*)(W3e + (t * 16 + lr) * 64 + k0 + quad * 8);
            acc3[t] = __builtin_amdgcn_mfma_f32_16x16x32_bf16(a, b, acc3[t], 0, 0, 0);
        }
    }
#pragma unroll
    for (int t = 0; t < 2; t++)
#pragma unroll
        for (int v = 0; v < 4; v++)
            h3s[wave][quad * 4 + v][t * 16 + lr] = f2bf(fmaxf(acc3[t][v], 0.f));

    // layer4 (M=16,N=14pad16,K=32): one MFMA
    f32x4 acc4;
    { float bb = (lr < 14) ? b4[e * 14 + lr] : 0.f; acc4 = (f32x4){bb, bb, bb, bb}; }
    {
        bf16x8 a = *(const bf16x8*)(&h3s[wave][lr][quad * 8]);
        bf16x8 b = *(const bf16x8*)(w4t + ((size_t)e * 16 + lr) * 32 + quad * 8);
        acc4 = __builtin_amdgcn_mfma_f32_16x16x32_bf16(a, b, acc4, 0, 0, 0);
    }

    // stores (masked): token row = quad*4+v
    const int* perm = ws_i + (WS_PERM >> 2);
#pragma unroll
    for (int v = 0; v < 4; v++) {
        int t = m0 + quad * 4 + v;
        if (t < len) {
            int token = perm[base + t];
            int bi = token >> 9, ni = token & 511;
            int valid = ni < lengths[bi];
            if (lr < 14) out[(size_t)token * 17 + lr] = valid ? acc4[v] : EPSV;
            if (lr < 3)  out[(size_t)token * 17 + 14 + lr] = valid ? accr[v] : EPSV;
        }
    }
}

extern "C" void kernel_launch(void* const* d_in, const int* in_sizes, int n_in,
                              void* d_out, int out_size, void* d_ws, size_t ws_size,
                              hipStream_t stream) {
    (void)in_sizes; (void)n_in; (void)out_size; (void)ws_size;
    const float* nodes   = (const float*)d_in[0];
    const int*   sem     = (const int*)d_in[1];
    const int*   lengths = (const int*)d_in[2];
    const float* W1 = (const float*)d_in[3];
    const float* b1 = (const float*)d_in[4];
    const float* W2 = (const float*)d_in[5];
    const float* b2 = (const float*)d_in[6];
    const float* W3 = (const float*)d_in[7];
    const float* b3 = (const float*)d_in[8];
    const float* W4 = (const float*)d_in[9];
    const float* b4 = (const float*)d_in[10];
    const float* R1  = (const float*)d_in[11];
    const float* rb1 = (const float*)d_in[12];
    const float* R2  = (const float*)d_in[13];
    const float* rb2 = (const float*)d_in[14];
    float* out = (float*)d_out;

    char* ws = (char*)d_ws;
    int* ws_i = (int*)ws;
    unsigned short* xs  = (unsigned short*)(ws + WS_XS);
    unsigned short* wt  = (unsigned short*)(ws + WS_WT);
    unsigned short* h1  = (unsigned short*)(ws + WS_H1);
    unsigned short* w2t = (unsigned short*)(ws + WS_W2T);
    unsigned short* w3t = (unsigned short*)(ws + WS_W3T);
    unsigned short* w4t = (unsigned short*)(ws + WS_W4T);
    unsigned short* r2t = (unsigned short*)(ws + WS_R2T);

    hipLaunchKernelGGL(k_zero, dim3(1), dim3(64), 0, stream, ws_i);
    hipLaunchKernelGGL(k_hist, dim3(64), dim3(256), 0, stream, sem, ws_i);
    hipLaunchKernelGGL(k_scan, dim3(1), dim3(64), 0, stream, ws_i);
    hipLaunchKernelGGL(k_scatter, dim3(64), dim3(256), 0, stream, sem, ws_i);
    hipLaunchKernelGGL(k_xgather, dim3(8192), dim3(256), 0, stream, nodes, (const int*)ws_i, xs);
    hipLaunchKernelGGL(k_wcvt, dim3(16, 8, 8), dim3(256), 0, stream, W1, R1, wt);
    hipLaunchKernelGGL(k_wcvt2, dim3(8), dim3(256), 0, stream, W2, W3, W4, R2, w2t, w3t, w4t, r2t);
    hipLaunchKernelGGL(k_gemm, dim3(MAXC128, 4), dim3(256), 0, stream,
                       (const unsigned short*)xs, (const unsigned short*)wt, b1, rb1,
                       (const int*)ws_i, h1);
    hipLaunchKernelGGL(k_tail, dim3(MAXC64), dim3(256), 0, stream,
                       (const unsigned short*)h1, (const int*)ws_i,
                       (const unsigned short*)w2t, (const unsigned short*)w3t,
                       (const unsigned short*)w4t, (const unsigned short*)r2t,
                       b2, b3, b4, rb2, lengths, out);
}